// Round 6
// baseline (322.931 us; speedup 1.0000x reference)
//
#include <hip/hip_runtime.h>
#include <hip/hip_bf16.h>
#include <math.h>

// Dims (compile-time constants for this problem)
#define Bb 2
#define Tt 1024
#define Dd 512
#define Hh 8
#define Kk 64
#define Vv 64
#define BT (Bb*Tt)          // 2048
#define HK (Hh*Kk)          // 512

// hyperparams
#define B1c 0.9f
#define B2c 0.999f
#define LRc 1e-3f
#define SCALEc 0.125f       // 64^-0.5

// ---------------------------------------------------------------------------
// fp32 tiled GEMM: C[M,N] = A[M,K] @ W[K,N], M=2048, N=512, K=512
// BM=BN=64, BK=16, 256 threads, 4x4 micro-tile per thread.
// ---------------------------------------------------------------------------
__device__ __forceinline__ void gemm_body(const float* __restrict__ A,
                                          const float* __restrict__ Bm,
                                          float* __restrict__ C) {
  constexpr int N = 512, Kd = 512;
  __shared__ float As[16][68];   // [k][m], padded
  __shared__ float Bs[16][68];   // [k][n]
  const int tid = threadIdx.x;
  const int bm = blockIdx.x * 64;
  const int bn = blockIdx.y * 64;
  const int tr = (tid >> 4) << 2;       // 0..60
  const int tc = (tid & 15) << 2;       // 0..60
  const int ar = tid >> 2;              // A tile row 0..63
  const int ak = (tid & 3) << 2;        // A tile k-col {0,4,8,12}
  const int bk = tid >> 4;              // B tile k-row 0..15
  const int bn4 = (tid & 15) << 2;      // B tile n-col
  float acc[4][4] = {};
  for (int k0 = 0; k0 < Kd; k0 += 16) {
    float4 av = *(const float4*)(A + (size_t)(bm + ar) * Kd + k0 + ak);
    float4 bv = *(const float4*)(Bm + (size_t)(k0 + bk) * N + bn + bn4);
    __syncthreads();
    As[ak + 0][ar] = av.x;
    As[ak + 1][ar] = av.y;
    As[ak + 2][ar] = av.z;
    As[ak + 3][ar] = av.w;
    *(float4*)&Bs[bk][bn4] = bv;
    __syncthreads();
#pragma unroll
    for (int kk = 0; kk < 16; ++kk) {
      float4 a = *(const float4*)&As[kk][tr];
      float4 b = *(const float4*)&Bs[kk][tc];
      const float ai[4] = {a.x, a.y, a.z, a.w};
      const float bj[4] = {b.x, b.y, b.z, b.w};
#pragma unroll
      for (int i = 0; i < 4; ++i)
#pragma unroll
        for (int j = 0; j < 4; ++j) acc[i][j] += ai[i] * bj[j];
    }
  }
#pragma unroll
  for (int i = 0; i < 4; ++i) {
    float4 o4 = {acc[i][0], acc[i][1], acc[i][2], acc[i][3]};
    *(float4*)(C + (size_t)(bm + tr + i) * N + bn + tc) = o4;
  }
}

__global__ __launch_bounds__(256) void gemm3_kernel(
    const float* __restrict__ x,
    const float* __restrict__ Wq, const float* __restrict__ Wk,
    const float* __restrict__ Wv,
    float* __restrict__ qp, float* __restrict__ kp, float* __restrict__ vp) {
  const float* W; float* Cp;
  if (blockIdx.z == 0)      { W = Wq; Cp = qp; }
  else if (blockIdx.z == 1) { W = Wk; Cp = kp; }
  else                      { W = Wv; Cp = vp; }
  gemm_body(x, W, Cp);
}

__global__ __launch_bounds__(256) void gemm1_kernel(
    const float* __restrict__ A, const float* __restrict__ W,
    float* __restrict__ C) {
  gemm_body(A, W, C);
}

// ---------------------------------------------------------------------------
// beta = sigmoid(x @ Wb), Wb:[512,8] -> beta:[B*T,8]
// ---------------------------------------------------------------------------
__global__ __launch_bounds__(256) void beta_kernel(const float* __restrict__ x,
                                                   const float* __restrict__ Wb,
                                                   float* __restrict__ beta) {
  int gid = blockIdx.x * blockDim.x + threadIdx.x;  // 0 .. 16383
  int bt = gid >> 3, h = gid & 7;
  const float* xr = x + (size_t)bt * Dd;
  float s = 0.f;
  for (int d = 0; d < Dd; ++d) s += xr[d] * Wb[d * Hh + h];
  beta[gid] = 1.f / (1.f + expf(-s));
}

// ---------------------------------------------------------------------------
// causal depthwise conv(4) + SiLU (+ optional L2 norm over K, + scale for q)
// ---------------------------------------------------------------------------
__global__ __launch_bounds__(256) void conv_kernel(
    const float* __restrict__ qp, const float* __restrict__ kp,
    const float* __restrict__ vp,
    const float* __restrict__ cwq, const float* __restrict__ cwk,
    const float* __restrict__ cwv,
    float* __restrict__ qc, float* __restrict__ kc, float* __restrict__ vc) {
  const int mode = blockIdx.z;
  const float* pre; const float* cw; float* post;
  if (mode == 0)      { pre = qp; cw = cwq; post = qc; }
  else if (mode == 1) { pre = kp; cw = cwk; post = kc; }
  else                { pre = vp; cw = cwv; post = vc; }

  const int idx = blockIdx.x * 4 + (threadIdx.x >> 6);   // (b,t,h) id, 0..16383
  const int lane = threadIdx.x & 63;
  const int b = idx >> 13;           // /(T*H)
  const int th = idx & 8191;
  const int t = th >> 3;
  const int h = th & 7;
  const int ch = h * 64 + lane;

  float y = 0.f;
#pragma unroll
  for (int i = 0; i < 4; ++i) {
    int tt = t + i - 3;
    if (tt >= 0)
      y += pre[((size_t)(b * Tt + tt)) * HK + ch] * cw[ch * 4 + i];
  }
  // SiLU
  y = y / (1.f + expf(-y));
  if (mode < 2) {
    float ss = y * y;
#pragma unroll
    for (int off = 32; off; off >>= 1) ss += __shfl_xor(ss, off, 64);
    y *= rsqrtf(ss + 1e-6f);
    if (mode == 0) y *= SCALEc;
  }
  post[((size_t)(b * Tt + t)) * HK + ch] = y;
}

// ---------------------------------------------------------------------------
// Butterfly partial sums, all-VALU-pipe.
// reduce32: sums within each 32-lane half (DPP xor1/2 + mirrors + permlane16).
// Stage validity: after each stage values are uniform within the sub-group,
// so any permutation crossing the next group works as the xor step.
// ---------------------------------------------------------------------------
template <int CTRL>
__device__ __forceinline__ float dpp_add(float v) {
  int y = __builtin_amdgcn_update_dpp(0, __float_as_int(v), CTRL, 0xF, 0xF, true);
  return v + __int_as_float(y);
}

typedef unsigned uint2_t __attribute__((ext_vector_type(2)));

__device__ __forceinline__ float xor16_add(float x) {
#if __has_builtin(__builtin_amdgcn_permlane16_swap)
  uint2_t r = __builtin_amdgcn_permlane16_swap(__float_as_uint(x), __float_as_uint(x),
                                               false, false);
  return __uint_as_float(r.x) + __uint_as_float(r.y);
#else
  int y = __builtin_amdgcn_ds_swizzle(__float_as_int(x), 0x401F);  // xor 16
  return x + __int_as_float(y);
#endif
}

__device__ __forceinline__ float reduce32(float x) {
  x = dpp_add<0xB1>(x);   // quad_perm xor 1
  x = dpp_add<0x4E>(x);   // quad_perm xor 2
  x = dpp_add<0x141>(x);  // row_half_mirror (crosses quads within 8)
  x = dpp_add<0x140>(x);  // row_mirror (crosses 8s within 16)
  x = xor16_add(x);       // crosses 16-rows within each 32-half
  return x;
}

// ---------------------------------------------------------------------------
// sequential IVON delta-rule scan.
// One wave handles TWO v-columns of one (b,h), packed into its 32-lane halves:
// lane = c*32 + kg; column v = p*2 + c; each lane holds k = {2kg, 2kg+1}.
// One reduce32 sequence computes BOTH columns' dot products simultaneously.
// k/q rows are shared by both halves (broadcast); state = 6 VGPRs/lane.
// 128 blocks x 4 waves = 512 waves = 2/CU on separate SIMDs.
// Depth-8 register prefetch hides L2/L3 load latency.
// ---------------------------------------------------------------------------
#define PD 8   // prefetch depth (steps)

__global__ __launch_bounds__(256) void scan_kernel(
    const float* __restrict__ qc, const float* __restrict__ kc,
    const float* __restrict__ vc, const float* __restrict__ beta,
    float* __restrict__ o) {
  const int lane = threadIdx.x & 63;
  const int widx = threadIdx.x >> 6;   // 0..3
  const int kg   = lane & 31;          // k-group: holds k = 2kg, 2kg+1
  const int c    = lane >> 5;          // which column of the pair
  const int bid = blockIdx.x;          // 0..127
  const int vq8 = bid >> 4;            // 0..7
  const int bh  = bid & 15;            // bid%8 == bh%8 -> same XCD per (b,h)
  const int b = bh >> 3, h = bh & 7;
  const int p = vq8 * 4 + widx;        // column pair 0..31
  const int v = p * 2 + c;             // 0..63

  const size_t base = ((size_t)b * Tt) * HK + h * 64;
  const float2* kp = (const float2*)(kc + base) + kg;
  const float2* qp = (const float2*)(qc + base) + kg;
  const float* vp = vc + base + v;
  const float* bp = beta + ((size_t)b * Tt) * Hh + h;
  float* op = o + base + v;

  float S0 = 0, S1 = 0, h0 = 0, h1 = 0, g0 = 0, g1 = 0;

  // depth-PD register prefetch (fully unrolled -> static indexing -> registers)
  float2 kb[PD], qb[PD];
  float  vb[PD], bb[PD];
#pragma unroll
  for (int i = 0; i < PD; ++i) {
    kb[i] = kp[(size_t)i * (HK / 2)];
    qb[i] = qp[(size_t)i * (HK / 2)];
    vb[i] = vp[(size_t)i * HK];
    bb[i] = bp[(size_t)i * Hh];
  }

  for (int t0 = 0; t0 < Tt; t0 += PD) {
#pragma unroll
    for (int i = 0; i < PD; ++i) {
      const int t = t0 + i;
      const float2 kv = kb[i], qv = qb[i];
      const float  vv = vb[i], bt = bb[i];
      int tp = t + PD; if (tp >= Tt) tp = Tt - 1;   // clamped dummy prefetch
      kb[i] = kp[(size_t)tp * (HK / 2)];
      qb[i] = qp[(size_t)tp * (HK / 2)];
      vb[i] = vp[(size_t)tp * HK];
      bb[i] = bp[(size_t)tp * Hh];

      float pred = reduce32(kv.x * S0 + kv.y * S1);
      float diff = pred - vv;
      float lrb = LRc * bt;
      float gr;
      gr = kv.x * diff;
      g0 = B1c * g0 + 0.1f * gr;
      h0 = B2c * h0 + 0.001f * (gr * gr);
      S0 -= lrb * g0 * __builtin_amdgcn_rcpf(h0 + 1.f);
      gr = kv.y * diff;
      g1 = B1c * g1 + 0.1f * gr;
      h1 = B2c * h1 + 0.001f * (gr * gr);
      S1 -= lrb * g1 * __builtin_amdgcn_rcpf(h1 + 1.f);
      float ov = reduce32(qv.x * S0 + qv.y * S1);
      if (kg == 0) op[(size_t)t * HK] = ov;   // lanes 0 and 32: one per column
    }
  }
}

// ---------------------------------------------------------------------------
// RMSNorm over V=64 (in-place), * rms_w
// ---------------------------------------------------------------------------
__global__ __launch_bounds__(256) void rmsnorm_kernel(float* __restrict__ o,
                                                      const float* __restrict__ rmsw) {
  const int idx = blockIdx.x * 4 + (threadIdx.x >> 6);  // (b,t,h), 0..16383
  const int lane = threadIdx.x & 63;
  float* p = o + (size_t)idx * 64;
  float y = p[lane];
  float ss = y * y;
#pragma unroll
  for (int off = 32; off; off >>= 1) ss += __shfl_xor(ss, off, 64);
  y = y * rsqrtf(ss * (1.f / 64.f) + 1e-5f) * rmsw[lane];
  p[lane] = y;
}

// ---------------------------------------------------------------------------
extern "C" void kernel_launch(void* const* d_in, const int* in_sizes, int n_in,
                              void* d_out, int out_size, void* d_ws, size_t ws_size,
                              hipStream_t stream) {
  const float* x    = (const float*)d_in[0];
  const float* Wq   = (const float*)d_in[1];
  const float* Wk   = (const float*)d_in[2];
  const float* Wv   = (const float*)d_in[3];
  const float* Wb   = (const float*)d_in[4];
  const float* cwq  = (const float*)d_in[5];
  const float* cwk  = (const float*)d_in[6];
  const float* cwv  = (const float*)d_in[7];
  const float* rmsw = (const float*)d_in[8];
  const float* Wo   = (const float*)d_in[9];
  float* out = (float*)d_out;
  float* ws  = (float*)d_ws;

  const size_t SZ = (size_t)BT * HK;   // 1,048,576 floats
  float* qp   = ws;            // pre-conv q   (later reused as scan output)
  float* kp   = ws + 1 * SZ;
  float* vp   = ws + 2 * SZ;
  float* qc   = ws + 3 * SZ;
  float* kc   = ws + 4 * SZ;
  float* vc   = ws + 5 * SZ;
  float* beta = ws + 6 * SZ;   // 16384 floats
  float* on   = qp;            // scan output / rmsnorm in-place (qp dead then)

  // 1. projections q,k,v
  gemm3_kernel<<<dim3(BT / 64, HK / 64, 3), 256, 0, stream>>>(x, Wq, Wk, Wv, qp, kp, vp);
  // 2. beta
  beta_kernel<<<dim3(BT * Hh / 256), 256, 0, stream>>>(x, Wb, beta);
  // 3. conv + silu + l2norm
  conv_kernel<<<dim3(Bb * Tt * Hh / 4, 1, 3), 256, 0, stream>>>(
      qp, kp, vp, cwq, cwk, cwv, qc, kc, vc);
  // 4. sequential scan: 128 blocks x 4 waves; each wave = 2 packed v-columns
  scan_kernel<<<dim3(Bb * Hh * (Vv / 8)), 256, 0, stream>>>(
      qc, kc, vc, beta, on);
  // 5. RMSNorm (in-place)
  rmsnorm_kernel<<<dim3(Bb * Tt * Hh / 4), 256, 0, stream>>>(on, rmsw);
  // 6. output projection
  gemm1_kernel<<<dim3(BT / 64, HK / 64, 1), 256, 0, stream>>>(on, Wo, out);
}

// Round 7
// 318.161 us; speedup vs baseline: 1.0150x; 1.0150x over previous
//
#include <hip/hip_runtime.h>
#include <hip/hip_bf16.h>
#include <math.h>

// Dims (compile-time constants for this problem)
#define Bb 2
#define Tt 1024
#define Dd 512
#define Hh 8
#define Kk 64
#define Vv 64
#define BT (Bb*Tt)          // 2048
#define HK (Hh*Kk)          // 512

// hyperparams
#define B1c 0.9f
#define B2c 0.999f
#define LRc 1e-3f
#define SCALEc 0.125f       // 64^-0.5

// ---------------------------------------------------------------------------
// fp32 tiled GEMM: C[M,N] = A[M,K] @ W[K,N], M=2048, N=512, K=512
// BM=BN=64, BK=16, 256 threads, 4x4 micro-tile per thread.
// ---------------------------------------------------------------------------
__device__ __forceinline__ void gemm_body(const float* __restrict__ A,
                                          const float* __restrict__ Bm,
                                          float* __restrict__ C) {
  constexpr int N = 512, Kd = 512;
  __shared__ float As[16][68];   // [k][m], padded
  __shared__ float Bs[16][68];   // [k][n]
  const int tid = threadIdx.x;
  const int bm = blockIdx.x * 64;
  const int bn = blockIdx.y * 64;
  const int tr = (tid >> 4) << 2;       // 0..60
  const int tc = (tid & 15) << 2;       // 0..60
  const int ar = tid >> 2;              // A tile row 0..63
  const int ak = (tid & 3) << 2;        // A tile k-col {0,4,8,12}
  const int bk = tid >> 4;              // B tile k-row 0..15
  const int bn4 = (tid & 15) << 2;      // B tile n-col
  float acc[4][4] = {};
  for (int k0 = 0; k0 < Kd; k0 += 16) {
    float4 av = *(const float4*)(A + (size_t)(bm + ar) * Kd + k0 + ak);
    float4 bv = *(const float4*)(Bm + (size_t)(k0 + bk) * N + bn + bn4);
    __syncthreads();
    As[ak + 0][ar] = av.x;
    As[ak + 1][ar] = av.y;
    As[ak + 2][ar] = av.z;
    As[ak + 3][ar] = av.w;
    *(float4*)&Bs[bk][bn4] = bv;
    __syncthreads();
#pragma unroll
    for (int kk = 0; kk < 16; ++kk) {
      float4 a = *(const float4*)&As[kk][tr];
      float4 b = *(const float4*)&Bs[kk][tc];
      const float ai[4] = {a.x, a.y, a.z, a.w};
      const float bj[4] = {b.x, b.y, b.z, b.w};
#pragma unroll
      for (int i = 0; i < 4; ++i)
#pragma unroll
        for (int j = 0; j < 4; ++j) acc[i][j] += ai[i] * bj[j];
    }
  }
#pragma unroll
  for (int i = 0; i < 4; ++i) {
    float4 o4 = {acc[i][0], acc[i][1], acc[i][2], acc[i][3]};
    *(float4*)(C + (size_t)(bm + tr + i) * N + bn + tc) = o4;
  }
}

__global__ __launch_bounds__(256) void gemm3_kernel(
    const float* __restrict__ x,
    const float* __restrict__ Wq, const float* __restrict__ Wk,
    const float* __restrict__ Wv,
    float* __restrict__ qp, float* __restrict__ kp, float* __restrict__ vp) {
  const float* W; float* Cp;
  if (blockIdx.z == 0)      { W = Wq; Cp = qp; }
  else if (blockIdx.z == 1) { W = Wk; Cp = kp; }
  else                      { W = Wv; Cp = vp; }
  gemm_body(x, W, Cp);
}

__global__ __launch_bounds__(256) void gemm1_kernel(
    const float* __restrict__ A, const float* __restrict__ W,
    float* __restrict__ C) {
  gemm_body(A, W, C);
}

// ---------------------------------------------------------------------------
// beta = sigmoid(x @ Wb), Wb:[512,8] -> beta:[B*T,8]
// ---------------------------------------------------------------------------
__global__ __launch_bounds__(256) void beta_kernel(const float* __restrict__ x,
                                                   const float* __restrict__ Wb,
                                                   float* __restrict__ beta) {
  int gid = blockIdx.x * blockDim.x + threadIdx.x;  // 0 .. 16383
  int bt = gid >> 3, h = gid & 7;
  const float* xr = x + (size_t)bt * Dd;
  float s = 0.f;
  for (int d = 0; d < Dd; ++d) s += xr[d] * Wb[d * Hh + h];
  beta[gid] = 1.f / (1.f + expf(-s));
}

// ---------------------------------------------------------------------------
// causal depthwise conv(4) + SiLU (+ optional L2 norm over K, + scale for q)
// ---------------------------------------------------------------------------
__global__ __launch_bounds__(256) void conv_kernel(
    const float* __restrict__ qp, const float* __restrict__ kp,
    const float* __restrict__ vp,
    const float* __restrict__ cwq, const float* __restrict__ cwk,
    const float* __restrict__ cwv,
    float* __restrict__ qc, float* __restrict__ kc, float* __restrict__ vc) {
  const int mode = blockIdx.z;
  const float* pre; const float* cw; float* post;
  if (mode == 0)      { pre = qp; cw = cwq; post = qc; }
  else if (mode == 1) { pre = kp; cw = cwk; post = kc; }
  else                { pre = vp; cw = cwv; post = vc; }

  const int idx = blockIdx.x * 4 + (threadIdx.x >> 6);   // (b,t,h) id, 0..16383
  const int lane = threadIdx.x & 63;
  const int b = idx >> 13;           // /(T*H)
  const int th = idx & 8191;
  const int t = th >> 3;
  const int h = th & 7;
  const int ch = h * 64 + lane;

  float y = 0.f;
#pragma unroll
  for (int i = 0; i < 4; ++i) {
    int tt = t + i - 3;
    if (tt >= 0)
      y += pre[((size_t)(b * Tt + tt)) * HK + ch] * cw[ch * 4 + i];
  }
  // SiLU
  y = y / (1.f + expf(-y));
  if (mode < 2) {
    float ss = y * y;
#pragma unroll
    for (int off = 32; off; off >>= 1) ss += __shfl_xor(ss, off, 64);
    y *= rsqrtf(ss + 1e-6f);
    if (mode == 0) y *= SCALEc;
  }
  post[((size_t)(b * Tt + t)) * HK + ch] = y;
}

// ---------------------------------------------------------------------------
// Butterfly partial sums, all-VALU-pipe.
// reduce32 stages: DPP xor1/2 + mirrors + permlane16_swap (sums each 32-half).
// ---------------------------------------------------------------------------
template <int CTRL>
__device__ __forceinline__ float dpp_add(float v) {
  int y = __builtin_amdgcn_update_dpp(0, __float_as_int(v), CTRL, 0xF, 0xF, true);
  return v + __int_as_float(y);
}

typedef unsigned uint2_t __attribute__((ext_vector_type(2)));

__device__ __forceinline__ float xor16_add(float x) {
#if __has_builtin(__builtin_amdgcn_permlane16_swap)
  uint2_t r = __builtin_amdgcn_permlane16_swap(__float_as_uint(x), __float_as_uint(x),
                                               false, false);
  return __uint_as_float(r.x) + __uint_as_float(r.y);
#else
  int y = __builtin_amdgcn_ds_swizzle(__float_as_int(x), 0x401F);  // xor 16
  return x + __int_as_float(y);
#endif
}

// ---------------------------------------------------------------------------
// sequential IVON delta-rule scan — correction-form recurrence.
//
// Layout (proven in R6): one wave = TWO v-columns of one (b,h); lane = c*32+kg,
// lane holds k = {2kg, 2kg+1}; column v = p*2 + c. reduce32 computes both
// columns' dot products simultaneously.
//
// Chain surgery: keep pred as a scalar recurrence
//   pred_{t+1} = A_t - lrb_t * R2_t,
//   A_t  = reduce(k_{t+1} · S_t)        (starts at step top, OFF-chain)
//   R2_t = reduce(k_{t+1} · w_t)        (the only reduce ON the chain)
//   S_{t+1} = S_t - lrb_t * w_t         (lane-local, canonical state)
//   o_t  = reduce(q_t · S_{t+1})        (OFF-chain, interleaved with R2)
// Exact algebra — no approximation, no error accumulation (A is fresh each step).
//
// Prefetch: depth-8 rotating register buffers; sched_barrier(0) after each
// slot's load group prevents the compiler from sinking the loads to their
// uses (R5/R6 showed VGPR=24/44 => buffers were NOT retained; the exposed
// ~266cy L2 latency per step was the dominant bubble).
// ---------------------------------------------------------------------------
#define PD 8   // prefetch depth (steps)

__global__ __launch_bounds__(256) void scan_kernel(
    const float* __restrict__ qc, const float* __restrict__ kc,
    const float* __restrict__ vc, const float* __restrict__ beta,
    float* __restrict__ o) {
  const int lane = threadIdx.x & 63;
  const int widx = threadIdx.x >> 6;   // 0..3
  const int kg   = lane & 31;          // k-group: holds k = 2kg, 2kg+1
  const int c    = lane >> 5;          // which column of the pair
  const int bid = blockIdx.x;          // 0..127
  const int vq8 = bid >> 4;            // 0..7
  const int bh  = bid & 15;            // bid%8 == bh%8 -> same XCD per (b,h)
  const int b = bh >> 3, h = bh & 7;
  const int p = vq8 * 4 + widx;        // column pair 0..31
  const int v = p * 2 + c;             // 0..63

  const size_t base = ((size_t)b * Tt) * HK + h * 64;
  const float2* kp = (const float2*)(kc + base) + kg;
  const float2* qp = (const float2*)(qc + base) + kg;
  const float* vp = vc + base + v;
  const float* bp = beta + ((size_t)b * Tt) * Hh + h;
  float* op = o + base + v;

  float S0 = 0, S1 = 0, h0 = 0, h1 = 0, g0 = 0, g1 = 0;
  float pred = 0.f;                    // pred_0 = k_0 . S_0 = 0

  // depth-PD register prefetch (fully unrolled -> static indexing -> registers)
  float2 kb[PD], qb[PD];
  float  vb[PD], bb[PD];
#pragma unroll
  for (int i = 0; i < PD; ++i) {
    kb[i] = kp[(size_t)i * (HK / 2)];
    qb[i] = qp[(size_t)i * (HK / 2)];
    vb[i] = vp[(size_t)i * HK];
    bb[i] = bp[(size_t)i * Hh];
  }

  for (int t0 = 0; t0 < Tt; t0 += PD) {
#pragma unroll
    for (int i = 0; i < PD; ++i) {
      const int t = t0 + i;
      // this step's operands (copied before slot overwrite)
      const float2 kv = kb[i], qv = qb[i];
      const float  vv = vb[i], bt = bb[i];
      // prefetch t+PD into slot i; fence so loads cannot sink into compute
      int tp = t + PD; if (tp >= Tt) tp = Tt - 1;
      kb[i] = kp[(size_t)tp * (HK / 2)];
      qb[i] = qp[(size_t)tp * (HK / 2)];
      vb[i] = vp[(size_t)tp * HK];
      bb[i] = bp[(size_t)tp * Hh];
      __builtin_amdgcn_sched_barrier(0);

      // k_{t+1}: slot (i+1)%PD. For i<PD-1 it still holds t+1; for i=PD-1,
      // slot 0 was overwritten earlier THIS block with t0+PD == t+1.
      const float2 k1 = kb[(i + 1) & (PD - 1)];

      // A_t = reduce(k_{t+1} . S_t) — off-chain, issued first
      float a = k1.x * S0 + k1.y * S1;

      // scalar chain head (uses pred from previous step)
      const float diff = pred - vv;
      const float lrb = LRc * bt;
      const float gr0 = kv.x * diff;
      const float gr1 = kv.y * diff;
      g0 = B1c * g0 + 0.1f * gr0;
      g1 = B1c * g1 + 0.1f * gr1;
      h0 = B2c * h0 + 0.001f * (gr0 * gr0);
      h1 = B2c * h1 + 0.001f * (gr1 * gr1);
      const float w0 = g0 * __builtin_amdgcn_rcpf(h0 + 1.f);
      const float w1 = g1 * __builtin_amdgcn_rcpf(h1 + 1.f);

      // A's reduce stages (independent of the w-chain; fill its bubbles)
      a = dpp_add<0xB1>(a);
      a = dpp_add<0x4E>(a);
      a = dpp_add<0x141>(a);
      a = dpp_add<0x140>(a);
      a = xor16_add(a);

      // canonical state update (off the pred chain)
      S0 -= lrb * w0;
      S1 -= lrb * w1;

      // R2 (on chain) and O (off chain), interleaved stage-by-stage
      float r2 = k1.x * w0 + k1.y * w1;
      float ro = qv.x * S0 + qv.y * S1;
      r2 = dpp_add<0xB1>(r2);   ro = dpp_add<0xB1>(ro);
      r2 = dpp_add<0x4E>(r2);   ro = dpp_add<0x4E>(ro);
      r2 = dpp_add<0x141>(r2);  ro = dpp_add<0x141>(ro);
      r2 = dpp_add<0x140>(r2);  ro = dpp_add<0x140>(ro);
      r2 = xor16_add(r2);       ro = xor16_add(ro);

      pred = a - lrb * r2;      // pred_{t+1} = k_{t+1} . S_{t+1}, exactly

      if (kg == 0) op[(size_t)t * HK] = ro;   // lanes 0 and 32: one per column
    }
  }
}

// ---------------------------------------------------------------------------
// RMSNorm over V=64 (in-place), * rms_w
// ---------------------------------------------------------------------------
__global__ __launch_bounds__(256) void rmsnorm_kernel(float* __restrict__ o,
                                                      const float* __restrict__ rmsw) {
  const int idx = blockIdx.x * 4 + (threadIdx.x >> 6);  // (b,t,h), 0..16383
  const int lane = threadIdx.x & 63;
  float* p = o + (size_t)idx * 64;
  float y = p[lane];
  float ss = y * y;
#pragma unroll
  for (int off = 32; off; off >>= 1) ss += __shfl_xor(ss, off, 64);
  y = y * rsqrtf(ss * (1.f / 64.f) + 1e-5f) * rmsw[lane];
  p[lane] = y;
}

// ---------------------------------------------------------------------------
extern "C" void kernel_launch(void* const* d_in, const int* in_sizes, int n_in,
                              void* d_out, int out_size, void* d_ws, size_t ws_size,
                              hipStream_t stream) {
  const float* x    = (const float*)d_in[0];
  const float* Wq   = (const float*)d_in[1];
  const float* Wk   = (const float*)d_in[2];
  const float* Wv   = (const float*)d_in[3];
  const float* Wb   = (const float*)d_in[4];
  const float* cwq  = (const float*)d_in[5];
  const float* cwk  = (const float*)d_in[6];
  const float* cwv  = (const float*)d_in[7];
  const float* rmsw = (const float*)d_in[8];
  const float* Wo   = (const float*)d_in[9];
  float* out = (float*)d_out;
  float* ws  = (float*)d_ws;

  const size_t SZ = (size_t)BT * HK;   // 1,048,576 floats
  float* qp   = ws;            // pre-conv q   (later reused as scan output)
  float* kp   = ws + 1 * SZ;
  float* vp   = ws + 2 * SZ;
  float* qc   = ws + 3 * SZ;
  float* kc   = ws + 4 * SZ;
  float* vc   = ws + 5 * SZ;
  float* beta = ws + 6 * SZ;   // 16384 floats
  float* on   = qp;            // scan output / rmsnorm in-place (qp dead then)

  // 1. projections q,k,v
  gemm3_kernel<<<dim3(BT / 64, HK / 64, 3), 256, 0, stream>>>(x, Wq, Wk, Wv, qp, kp, vp);
  // 2. beta
  beta_kernel<<<dim3(BT * Hh / 256), 256, 0, stream>>>(x, Wb, beta);
  // 3. conv + silu + l2norm
  conv_kernel<<<dim3(Bb * Tt * Hh / 4, 1, 3), 256, 0, stream>>>(
      qp, kp, vp, cwq, cwk, cwv, qc, kc, vc);
  // 4. sequential scan: 128 blocks x 4 waves; each wave = 2 packed v-columns
  scan_kernel<<<dim3(Bb * Hh * (Vv / 8)), 256, 0, stream>>>(
      qc, kc, vc, beta, on);
  // 5. RMSNorm (in-place)
  rmsnorm_kernel<<<dim3(Bb * Tt * Hh / 4), 256, 0, stream>>>(on, rmsw);
  // 6. output projection
  gemm1_kernel<<<dim3(BT / 64, HK / 64, 1), 256, 0, stream>>>(on, Wo, out);
}

// Round 8
// 291.938 us; speedup vs baseline: 1.1062x; 1.0898x over previous
//
#include <hip/hip_runtime.h>
#include <hip/hip_bf16.h>
#include <math.h>

// Dims (compile-time constants for this problem)
#define Bb 2
#define Tt 1024
#define Dd 512
#define Hh 8
#define Kk 64
#define Vv 64
#define BT (Bb*Tt)          // 2048
#define HK (Hh*Kk)          // 512

// hyperparams
#define B1c 0.9f
#define B2c 0.999f
#define LRc 1e-3f
#define SCALEc 0.125f       // 64^-0.5

// ---------------------------------------------------------------------------
// fp32 tiled GEMM: C[M,N] = A[M,K] @ W[K,N], M=2048, N=512, K=512
// ---------------------------------------------------------------------------
__device__ __forceinline__ void gemm_body(const float* __restrict__ A,
                                          const float* __restrict__ Bm,
                                          float* __restrict__ C) {
  constexpr int N = 512, Kd = 512;
  __shared__ float As[16][68];   // [k][m], padded
  __shared__ float Bs[16][68];   // [k][n]
  const int tid = threadIdx.x;
  const int bm = blockIdx.x * 64;
  const int bn = blockIdx.y * 64;
  const int tr = (tid >> 4) << 2;       // 0..60
  const int tc = (tid & 15) << 2;       // 0..60
  const int ar = tid >> 2;              // A tile row 0..63
  const int ak = (tid & 3) << 2;        // A tile k-col {0,4,8,12}
  const int bk = tid >> 4;              // B tile k-row 0..15
  const int bn4 = (tid & 15) << 2;      // B tile n-col
  float acc[4][4] = {};
  for (int k0 = 0; k0 < Kd; k0 += 16) {
    float4 av = *(const float4*)(A + (size_t)(bm + ar) * Kd + k0 + ak);
    float4 bv = *(const float4*)(Bm + (size_t)(k0 + bk) * N + bn + bn4);
    __syncthreads();
    As[ak + 0][ar] = av.x;
    As[ak + 1][ar] = av.y;
    As[ak + 2][ar] = av.z;
    As[ak + 3][ar] = av.w;
    *(float4*)&Bs[bk][bn4] = bv;
    __syncthreads();
#pragma unroll
    for (int kk = 0; kk < 16; ++kk) {
      float4 a = *(const float4*)&As[kk][tr];
      float4 b = *(const float4*)&Bs[kk][tc];
      const float ai[4] = {a.x, a.y, a.z, a.w};
      const float bj[4] = {b.x, b.y, b.z, b.w};
#pragma unroll
      for (int i = 0; i < 4; ++i)
#pragma unroll
        for (int j = 0; j < 4; ++j) acc[i][j] += ai[i] * bj[j];
    }
  }
#pragma unroll
  for (int i = 0; i < 4; ++i) {
    float4 o4 = {acc[i][0], acc[i][1], acc[i][2], acc[i][3]};
    *(float4*)(C + (size_t)(bm + tr + i) * N + bn + tc) = o4;
  }
}

__global__ __launch_bounds__(256) void gemm3_kernel(
    const float* __restrict__ x,
    const float* __restrict__ Wq, const float* __restrict__ Wk,
    const float* __restrict__ Wv,
    float* __restrict__ qp, float* __restrict__ kp, float* __restrict__ vp) {
  const float* W; float* Cp;
  if (blockIdx.z == 0)      { W = Wq; Cp = qp; }
  else if (blockIdx.z == 1) { W = Wk; Cp = kp; }
  else                      { W = Wv; Cp = vp; }
  gemm_body(x, W, Cp);
}

__global__ __launch_bounds__(256) void gemm1_kernel(
    const float* __restrict__ A, const float* __restrict__ W,
    float* __restrict__ C) {
  gemm_body(A, W, C);
}

// ---------------------------------------------------------------------------
// beta = sigmoid(x @ Wb), Wb:[512,8] -> beta:[B*T,8]
// ---------------------------------------------------------------------------
__global__ __launch_bounds__(256) void beta_kernel(const float* __restrict__ x,
                                                   const float* __restrict__ Wb,
                                                   float* __restrict__ beta) {
  int gid = blockIdx.x * blockDim.x + threadIdx.x;  // 0 .. 16383
  int bt = gid >> 3, h = gid & 7;
  const float* xr = x + (size_t)bt * Dd;
  float s = 0.f;
  for (int d = 0; d < Dd; ++d) s += xr[d] * Wb[d * Hh + h];
  beta[gid] = 1.f / (1.f + expf(-s));
}

// ---------------------------------------------------------------------------
// causal depthwise conv(4) + SiLU (+ optional L2 norm over K, + scale for q)
// ---------------------------------------------------------------------------
__global__ __launch_bounds__(256) void conv_kernel(
    const float* __restrict__ qp, const float* __restrict__ kp,
    const float* __restrict__ vp,
    const float* __restrict__ cwq, const float* __restrict__ cwk,
    const float* __restrict__ cwv,
    float* __restrict__ qc, float* __restrict__ kc, float* __restrict__ vc) {
  const int mode = blockIdx.z;
  const float* pre; const float* cw; float* post;
  if (mode == 0)      { pre = qp; cw = cwq; post = qc; }
  else if (mode == 1) { pre = kp; cw = cwk; post = kc; }
  else                { pre = vp; cw = cwv; post = vc; }

  const int idx = blockIdx.x * 4 + (threadIdx.x >> 6);   // (b,t,h) id, 0..16383
  const int lane = threadIdx.x & 63;
  const int b = idx >> 13;           // /(T*H)
  const int th = idx & 8191;
  const int t = th >> 3;
  const int h = th & 7;
  const int ch = h * 64 + lane;

  float y = 0.f;
#pragma unroll
  for (int i = 0; i < 4; ++i) {
    int tt = t + i - 3;
    if (tt >= 0)
      y += pre[((size_t)(b * Tt + tt)) * HK + ch] * cw[ch * 4 + i];
  }
  // SiLU
  y = y / (1.f + expf(-y));
  if (mode < 2) {
    float ss = y * y;
#pragma unroll
    for (int off = 32; off; off >>= 1) ss += __shfl_xor(ss, off, 64);
    y *= rsqrtf(ss + 1e-6f);
    if (mode == 0) y *= SCALEc;
  }
  post[((size_t)(b * Tt + t)) * HK + ch] = y;
}

// ---------------------------------------------------------------------------
// Butterfly partial sums, all-VALU-pipe.
// reduce32: sums within each 32-lane half (DPP xor1/2 + mirrors + permlane16).
// ---------------------------------------------------------------------------
template <int CTRL>
__device__ __forceinline__ float dpp_add(float v) {
  int y = __builtin_amdgcn_update_dpp(0, __float_as_int(v), CTRL, 0xF, 0xF, true);
  return v + __int_as_float(y);
}

typedef unsigned uint2_t __attribute__((ext_vector_type(2)));

__device__ __forceinline__ float xor16_add(float x) {
#if __has_builtin(__builtin_amdgcn_permlane16_swap)
  uint2_t r = __builtin_amdgcn_permlane16_swap(__float_as_uint(x), __float_as_uint(x),
                                               false, false);
  return __uint_as_float(r.x) + __uint_as_float(r.y);
#else
  int y = __builtin_amdgcn_ds_swizzle(__float_as_int(x), 0x401F);  // xor 16
  return x + __int_as_float(y);
#endif
}

__device__ __forceinline__ float reduce32(float x) {
  x = dpp_add<0xB1>(x);   // quad_perm xor 1
  x = dpp_add<0x4E>(x);   // quad_perm xor 2
  x = dpp_add<0x141>(x);  // row_half_mirror (xor 4)
  x = dpp_add<0x140>(x);  // row_mirror (xor 8)
  x = xor16_add(x);       // xor 16 -> each 32-half holds its own total
  return x;
}

// ---------------------------------------------------------------------------
// sequential IVON delta-rule scan — LDS-staged operands.
//
// One block (256 thr = 4 waves) owns one (b,h) and 8 v-columns; each wave
// packs 2 v-columns into its 32-lane halves (lane = c*32+kg, k = {2kg,2kg+1}).
// Per 32-step tile, the block cooperatively stages k,q (shared), its v-slice
// and LRc*beta into a double-buffered LDS tile. Staging loads are issued
// BEFORE the 32-step compute and ds_written AFTER it (issue-early/write-late:
// ~5000 cy of compute hides the HBM/L2 latency). Inner loop reads operands
// with ds_read + immediate offsets: no per-step address math, ~120cy LDS
// latency easily hidden by the compiler's fine-grained lgkmcnt scheduling.
// Grid: 128 blocks; bid%8 == bh%8 pins each (b,h) to one XCD's L2.
// ---------------------------------------------------------------------------
#define TC 32   // steps per LDS tile

__global__ __launch_bounds__(256) void scan_kernel(
    const float* __restrict__ qc, const float* __restrict__ kc,
    const float* __restrict__ vc, const float* __restrict__ beta,
    float* __restrict__ o) {
  __shared__ float ks[2][TC][64];
  __shared__ float qs[2][TC][64];
  __shared__ float vs[2][TC][8];
  __shared__ float bs[2][TC];

  const int tid  = threadIdx.x;
  const int lane = tid & 63;
  const int w    = tid >> 6;          // wave 0..3
  const int kg   = lane & 31;         // k-group: holds k = 2kg, 2kg+1
  const int c    = lane >> 5;         // column within pair
  const int bid  = blockIdx.x;        // 0..127
  const int vq8  = bid >> 4;          // 0..7  (column octet)
  const int bh   = bid & 15;          // bid%8 == bh%8 -> XCD affinity
  const int b = bh >> 3, h = bh & 7;
  const int colbase = vq8 * 8;
  const int cc = w * 2 + c;           // column within block 0..7
  const int v  = colbase + cc;        // global v column 0..63

  const size_t base2 = ((size_t)b * Tt) * HK + h * 64;
  const float* bp = beta + ((size_t)b * Tt) * Hh + h;
  float* op = o + base2 + v;

  // staging thread mapping
  const int sr = tid >> 4;            // k/q row 0..15 (and +16)
  const int sq = (tid & 15) * 4;      // k/q col (float)
  const int vr = tid >> 3;            // v row 0..31
  const int v8 = tid & 7;             // v col 0..7

  // ---- prologue: stage tile 0 into buffer 0 ----
  {
    float4 k0 = *(const float4*)(kc + base2 + (size_t)sr * HK + sq);
    float4 k1 = *(const float4*)(kc + base2 + (size_t)(sr + 16) * HK + sq);
    float4 q0 = *(const float4*)(qc + base2 + (size_t)sr * HK + sq);
    float4 q1 = *(const float4*)(qc + base2 + (size_t)(sr + 16) * HK + sq);
    float  vv = vc[base2 + (size_t)vr * HK + colbase + v8];
    float  bb = (tid < TC) ? LRc * bp[(size_t)tid * Hh] : 0.f;
    *(float4*)&ks[0][sr][sq] = k0;
    *(float4*)&ks[0][sr + 16][sq] = k1;
    *(float4*)&qs[0][sr][sq] = q0;
    *(float4*)&qs[0][sr + 16][sq] = q1;
    vs[0][vr][v8] = vv;
    if (tid < TC) bs[0][tid] = bb;
    __syncthreads();
  }

  float S0 = 0, S1 = 0, h0 = 0, h1 = 0, g0 = 0, g1 = 0;

  for (int tile = 0; tile < Tt / TC; ++tile) {
    const int d = tile & 1;
    const int t0 = tile * TC;
    const int more = (tile + 1 < Tt / TC);
    const int tn = more ? t0 + TC : t0;   // clamped (rewrite same tile, unused)

    // issue next tile's global loads NOW (completion hidden under compute)
    float4 nk0 = *(const float4*)(kc + base2 + (size_t)(tn + sr) * HK + sq);
    float4 nk1 = *(const float4*)(kc + base2 + (size_t)(tn + sr + 16) * HK + sq);
    float4 nq0 = *(const float4*)(qc + base2 + (size_t)(tn + sr) * HK + sq);
    float4 nq1 = *(const float4*)(qc + base2 + (size_t)(tn + sr + 16) * HK + sq);
    float  nv  = vc[base2 + (size_t)(tn + vr) * HK + colbase + v8];
    float  nb  = (tid < TC) ? LRc * bp[(size_t)(tn + tid) * Hh] : 0.f;

    // 32 steps from buffer d (all operands via ds_read + imm offsets)
#pragma unroll
    for (int s = 0; s < TC; ++s) {
      const float2 kv = *(const float2*)&ks[d][s][kg * 2];
      const float2 qv = *(const float2*)&qs[d][s][kg * 2];
      const float  vv = vs[d][s][cc];
      const float  lrb = bs[d][s];

      const float pred = reduce32(kv.x * S0 + kv.y * S1);
      const float diff = pred - vv;
      const float gr0 = kv.x * diff;
      const float gr1 = kv.y * diff;
      g0 = B1c * g0 + 0.1f * gr0;
      g1 = B1c * g1 + 0.1f * gr1;
      h0 = B2c * h0 + 0.001f * (gr0 * gr0);
      h1 = B2c * h1 + 0.001f * (gr1 * gr1);
      S0 -= lrb * g0 * __builtin_amdgcn_rcpf(h0 + 1.f);
      S1 -= lrb * g1 * __builtin_amdgcn_rcpf(h1 + 1.f);
      const float ro = reduce32(qv.x * S0 + qv.y * S1);
      if (kg == 0) op[(size_t)(t0 + s) * HK] = ro;  // lanes 0,32: one per col
    }

    // write next tile into the other buffer; single barrier per tile
    if (more) {
      *(float4*)&ks[d ^ 1][sr][sq] = nk0;
      *(float4*)&ks[d ^ 1][sr + 16][sq] = nk1;
      *(float4*)&qs[d ^ 1][sr][sq] = nq0;
      *(float4*)&qs[d ^ 1][sr + 16][sq] = nq1;
      vs[d ^ 1][vr][v8] = nv;
      if (tid < TC) bs[d ^ 1][tid] = nb;
    }
    __syncthreads();
  }
}

// ---------------------------------------------------------------------------
// RMSNorm over V=64 (in-place), * rms_w
// ---------------------------------------------------------------------------
__global__ __launch_bounds__(256) void rmsnorm_kernel(float* __restrict__ o,
                                                      const float* __restrict__ rmsw) {
  const int idx = blockIdx.x * 4 + (threadIdx.x >> 6);  // (b,t,h), 0..16383
  const int lane = threadIdx.x & 63;
  float* p = o + (size_t)idx * 64;
  float y = p[lane];
  float ss = y * y;
#pragma unroll
  for (int off = 32; off; off >>= 1) ss += __shfl_xor(ss, off, 64);
  y = y * rsqrtf(ss * (1.f / 64.f) + 1e-5f) * rmsw[lane];
  p[lane] = y;
}

// ---------------------------------------------------------------------------
extern "C" void kernel_launch(void* const* d_in, const int* in_sizes, int n_in,
                              void* d_out, int out_size, void* d_ws, size_t ws_size,
                              hipStream_t stream) {
  const float* x    = (const float*)d_in[0];
  const float* Wq   = (const float*)d_in[1];
  const float* Wk   = (const float*)d_in[2];
  const float* Wv   = (const float*)d_in[3];
  const float* Wb   = (const float*)d_in[4];
  const float* cwq  = (const float*)d_in[5];
  const float* cwk  = (const float*)d_in[6];
  const float* cwv  = (const float*)d_in[7];
  const float* rmsw = (const float*)d_in[8];
  const float* Wo   = (const float*)d_in[9];
  float* out = (float*)d_out;
  float* ws  = (float*)d_ws;

  const size_t SZ = (size_t)BT * HK;   // 1,048,576 floats
  float* qp   = ws;            // pre-conv q   (later reused as scan output)
  float* kp   = ws + 1 * SZ;
  float* vp   = ws + 2 * SZ;
  float* qc   = ws + 3 * SZ;
  float* kc   = ws + 4 * SZ;
  float* vc   = ws + 5 * SZ;
  float* beta = ws + 6 * SZ;   // 16384 floats
  float* on   = qp;            // scan output / rmsnorm in-place (qp dead then)

  // 1. projections q,k,v
  gemm3_kernel<<<dim3(BT / 64, HK / 64, 3), 256, 0, stream>>>(x, Wq, Wk, Wv, qp, kp, vp);
  // 2. beta
  beta_kernel<<<dim3(BT * Hh / 256), 256, 0, stream>>>(x, Wb, beta);
  // 3. conv + silu + l2norm
  conv_kernel<<<dim3(Bb * Tt * Hh / 4, 1, 3), 256, 0, stream>>>(
      qp, kp, vp, cwq, cwk, cwv, qc, kc, vc);
  // 4. sequential scan: 128 blocks x 4 waves; LDS-staged operands
  scan_kernel<<<dim3(Bb * Hh * (Vv / 8)), 256, 0, stream>>>(
      qc, kc, vc, beta, on);
  // 5. RMSNorm (in-place)
  rmsnorm_kernel<<<dim3(Bb * Tt * Hh / 4), 256, 0, stream>>>(on, rmsw);
  // 6. output projection
  gemm1_kernel<<<dim3(BT / 64, HK / 64, 1), 256, 0, stream>>>(on, Wo, out);
}

// Round 9
// 291.092 us; speedup vs baseline: 1.1094x; 1.0029x over previous
//
#include <hip/hip_runtime.h>
#include <hip/hip_bf16.h>
#include <math.h>

// Dims (compile-time constants for this problem)
#define Bb 2
#define Tt 1024
#define Dd 512
#define Hh 8
#define Kk 64
#define Vv 64
#define BT (Bb*Tt)          // 2048
#define HK (Hh*Kk)          // 512

// hyperparams
#define B1c 0.9f
#define B2c 0.999f
#define LRc 1e-3f
#define SCALEc 0.125f       // 64^-0.5

// ---------------------------------------------------------------------------
// fp32 tiled GEMM: C[M,N] = A[M,K] @ W[K,N], M=2048, N=512, K=512
// ---------------------------------------------------------------------------
__device__ __forceinline__ void gemm_body(const float* __restrict__ A,
                                          const float* __restrict__ Bm,
                                          float* __restrict__ C) {
  constexpr int N = 512, Kd = 512;
  __shared__ float As[16][68];   // [k][m], padded
  __shared__ float Bs[16][68];   // [k][n]
  const int tid = threadIdx.x;
  const int bm = blockIdx.x * 64;
  const int bn = blockIdx.y * 64;
  const int tr = (tid >> 4) << 2;       // 0..60
  const int tc = (tid & 15) << 2;       // 0..60
  const int ar = tid >> 2;              // A tile row 0..63
  const int ak = (tid & 3) << 2;        // A tile k-col {0,4,8,12}
  const int bk = tid >> 4;              // B tile k-row 0..15
  const int bn4 = (tid & 15) << 2;      // B tile n-col
  float acc[4][4] = {};
  for (int k0 = 0; k0 < Kd; k0 += 16) {
    float4 av = *(const float4*)(A + (size_t)(bm + ar) * Kd + k0 + ak);
    float4 bv = *(const float4*)(Bm + (size_t)(k0 + bk) * N + bn + bn4);
    __syncthreads();
    As[ak + 0][ar] = av.x;
    As[ak + 1][ar] = av.y;
    As[ak + 2][ar] = av.z;
    As[ak + 3][ar] = av.w;
    *(float4*)&Bs[bk][bn4] = bv;
    __syncthreads();
#pragma unroll
    for (int kk = 0; kk < 16; ++kk) {
      float4 a = *(const float4*)&As[kk][tr];
      float4 b = *(const float4*)&Bs[kk][tc];
      const float ai[4] = {a.x, a.y, a.z, a.w};
      const float bj[4] = {b.x, b.y, b.z, b.w};
#pragma unroll
      for (int i = 0; i < 4; ++i)
#pragma unroll
        for (int j = 0; j < 4; ++j) acc[i][j] += ai[i] * bj[j];
    }
  }
#pragma unroll
  for (int i = 0; i < 4; ++i) {
    float4 o4 = {acc[i][0], acc[i][1], acc[i][2], acc[i][3]};
    *(float4*)(C + (size_t)(bm + tr + i) * N + bn + tc) = o4;
  }
}

__global__ __launch_bounds__(256) void gemm3_kernel(
    const float* __restrict__ x,
    const float* __restrict__ Wq, const float* __restrict__ Wk,
    const float* __restrict__ Wv,
    float* __restrict__ qp, float* __restrict__ kp, float* __restrict__ vp) {
  const float* W; float* Cp;
  if (blockIdx.z == 0)      { W = Wq; Cp = qp; }
  else if (blockIdx.z == 1) { W = Wk; Cp = kp; }
  else                      { W = Wv; Cp = vp; }
  gemm_body(x, W, Cp);
}

__global__ __launch_bounds__(256) void gemm1_kernel(
    const float* __restrict__ A, const float* __restrict__ W,
    float* __restrict__ C) {
  gemm_body(A, W, C);
}

// ---------------------------------------------------------------------------
// beta = sigmoid(x @ Wb), Wb:[512,8] -> beta:[B*T,8]
// ---------------------------------------------------------------------------
__global__ __launch_bounds__(256) void beta_kernel(const float* __restrict__ x,
                                                   const float* __restrict__ Wb,
                                                   float* __restrict__ beta) {
  int gid = blockIdx.x * blockDim.x + threadIdx.x;  // 0 .. 16383
  int bt = gid >> 3, h = gid & 7;
  const float* xr = x + (size_t)bt * Dd;
  float s = 0.f;
  for (int d = 0; d < Dd; ++d) s += xr[d] * Wb[d * Hh + h];
  beta[gid] = 1.f / (1.f + expf(-s));
}

// ---------------------------------------------------------------------------
// causal depthwise conv(4) + SiLU (+ optional L2 norm over K, + scale for q)
// ---------------------------------------------------------------------------
__global__ __launch_bounds__(256) void conv_kernel(
    const float* __restrict__ qp, const float* __restrict__ kp,
    const float* __restrict__ vp,
    const float* __restrict__ cwq, const float* __restrict__ cwk,
    const float* __restrict__ cwv,
    float* __restrict__ qc, float* __restrict__ kc, float* __restrict__ vc) {
  const int mode = blockIdx.z;
  const float* pre; const float* cw; float* post;
  if (mode == 0)      { pre = qp; cw = cwq; post = qc; }
  else if (mode == 1) { pre = kp; cw = cwk; post = kc; }
  else                { pre = vp; cw = cwv; post = vc; }

  const int idx = blockIdx.x * 4 + (threadIdx.x >> 6);   // (b,t,h) id, 0..16383
  const int lane = threadIdx.x & 63;
  const int b = idx >> 13;           // /(T*H)
  const int th = idx & 8191;
  const int t = th >> 3;
  const int h = th & 7;
  const int ch = h * 64 + lane;

  float y = 0.f;
#pragma unroll
  for (int i = 0; i < 4; ++i) {
    int tt = t + i - 3;
    if (tt >= 0)
      y += pre[((size_t)(b * Tt + tt)) * HK + ch] * cw[ch * 4 + i];
  }
  // SiLU
  y = y / (1.f + expf(-y));
  if (mode < 2) {
    float ss = y * y;
#pragma unroll
    for (int off = 32; off; off >>= 1) ss += __shfl_xor(ss, off, 64);
    y *= rsqrtf(ss + 1e-6f);
    if (mode == 0) y *= SCALEc;
  }
  post[((size_t)(b * Tt + t)) * HK + ch] = y;
}

// ---------------------------------------------------------------------------
// Butterfly partial sums, all-VALU-pipe.
// reduce32: sums within each 32-lane half (DPP xor1/2 + mirrors + permlane16).
// ---------------------------------------------------------------------------
template <int CTRL>
__device__ __forceinline__ float dpp_add(float v) {
  int y = __builtin_amdgcn_update_dpp(0, __float_as_int(v), CTRL, 0xF, 0xF, true);
  return v + __int_as_float(y);
}

typedef unsigned uint2_t __attribute__((ext_vector_type(2)));

__device__ __forceinline__ float xor16_add(float x) {
#if __has_builtin(__builtin_amdgcn_permlane16_swap)
  uint2_t r = __builtin_amdgcn_permlane16_swap(__float_as_uint(x), __float_as_uint(x),
                                               false, false);
  return __uint_as_float(r.x) + __uint_as_float(r.y);
#else
  int y = __builtin_amdgcn_ds_swizzle(__float_as_int(x), 0x401F);  // xor 16
  return x + __int_as_float(y);
#endif
}

__device__ __forceinline__ float reduce32(float x) {
  x = dpp_add<0xB1>(x);   // quad_perm xor 1
  x = dpp_add<0x4E>(x);   // quad_perm xor 2
  x = dpp_add<0x141>(x);  // row_half_mirror (xor 4)
  x = dpp_add<0x140>(x);  // row_mirror (xor 8)
  x = xor16_add(x);       // xor 16 -> each 32-half holds its own total
  return x;
}

// ---------------------------------------------------------------------------
// sequential IVON delta-rule scan — LDS-staged, PACKED operands + reg pipeline.
//
// One block (256 thr = 4 waves) owns one (b,h) and 8 v-columns; each wave
// packs 2 v-columns into its 32-lane halves (lane = c*32+kg, k = {2kg,2kg+1}).
//
// R8 post-mortem: per-step wall 427cy = issue ~170 + wait ~250; the wait is
// ds_read latency issued-at-use (VGPR=52: nothing held in flight) + chain
// clustering. Fixes here:
//  * k,q packed as ONE float4/lane (ds_read_b128) and v+LRc*beta as ONE
//    broadcast float2 -> 2 ds_reads/step instead of 4.
//  * explicit LDS->reg prefetch: step s+1's reads issued before step s's
//    compute (named SSA regs in the unrolled body) -> ~150cy distance > 120cy
//    LDS latency.
//  * TC=16, double-buffered (34KB LDS), one barrier per tile,
//    issue-early/write-late global staging unchanged.
// ---------------------------------------------------------------------------
#define TC 16   // steps per LDS tile

__global__ __launch_bounds__(256) void scan_kernel(
    const float* __restrict__ qc, const float* __restrict__ kc,
    const float* __restrict__ vc, const float* __restrict__ beta,
    float* __restrict__ o) {
  __shared__ float4 kq[2][TC][64];   // {k0,k1,q0,q1} per k-pair
  __shared__ float2 vb[2][TC][8];    // {v[col], LRc*beta} per column

  const int tid  = threadIdx.x;
  const int lane = tid & 63;
  const int w    = tid >> 6;          // wave 0..3
  const int kg   = lane & 31;         // k-group: holds k = 2kg, 2kg+1
  const int c    = lane >> 5;         // column within pair
  const int bid  = blockIdx.x;        // 0..127
  const int vq8  = bid >> 4;          // 0..7  (column octet)
  const int bh   = bid & 15;          // bid%8 == bh%8 -> XCD affinity
  const int b = bh >> 3, h = bh & 7;
  const int colbase = vq8 * 8;
  const int cc = w * 2 + c;           // column within block 0..7
  const int v  = colbase + cc;        // global v column 0..63

  const size_t base2 = ((size_t)b * Tt) * HK + h * 64;
  const float* bp = beta + ((size_t)b * Tt) * Hh + h;
  float* op = o + base2 + v;

  // staging thread mapping: k/q rows (16 per tile)
  const int sr = tid >> 4;            // row 0..15
  const int sm = tid & 15;            // float4 col group (k cols 4sm..4sm+3)
  // v/beta staging: first 128 threads
  const int vr = tid >> 3;            // row 0..15 (tid<128)
  const int v8 = tid & 7;             // col 0..7

  // ---- prologue: stage tile 0 into buffer 0 ----
  {
    float4 k4 = *(const float4*)(kc + base2 + (size_t)sr * HK + sm * 4);
    float4 q4 = *(const float4*)(qc + base2 + (size_t)sr * HK + sm * 4);
    kq[0][sr][sm * 2 + 0] = make_float4(k4.x, k4.y, q4.x, q4.y);
    kq[0][sr][sm * 2 + 1] = make_float4(k4.z, k4.w, q4.z, q4.w);
    if (tid < 128) {
      float vv = vc[base2 + (size_t)vr * HK + colbase + v8];
      float lb = LRc * bp[(size_t)vr * Hh];
      vb[0][vr][v8] = make_float2(vv, lb);
    }
    __syncthreads();
  }

  float S0 = 0, S1 = 0, h0 = 0, h1 = 0, g0 = 0, g1 = 0;

  for (int tile = 0; tile < Tt / TC; ++tile) {
    const int d = tile & 1;
    const int t0 = tile * TC;
    const int more = (tile + 1 < Tt / TC);
    const int tn = more ? t0 + TC : t0;   // clamped (rewrite same tile, unused)

    // issue next tile's global loads NOW (completion hidden under compute)
    float4 nk = *(const float4*)(kc + base2 + (size_t)(tn + sr) * HK + sm * 4);
    float4 nq = *(const float4*)(qc + base2 + (size_t)(tn + sr) * HK + sm * 4);
    float  nv = 0.f, nb = 0.f;
    if (tid < 128) {
      nv = vc[base2 + (size_t)(tn + vr) * HK + colbase + v8];
      nb = LRc * bp[(size_t)(tn + vr) * Hh];
    }

    // 16 steps from buffer d; LDS->reg prefetch one step ahead
    float4 kqc = kq[d][0][kg];
    float2 vbc = vb[d][0][cc];
#pragma unroll
    for (int s = 0; s < TC; ++s) {
      float4 kqn; float2 vbn;
      if (s + 1 < TC) {
        kqn = kq[d][s + 1][kg];
        vbn = vb[d][s + 1][cc];
      }
      const float kvx = kqc.x, kvy = kqc.y, qvx = kqc.z, qvy = kqc.w;
      const float vv = vbc.x, lrb = vbc.y;

      const float pred = reduce32(kvx * S0 + kvy * S1);
      const float diff = pred - vv;
      const float gr0 = kvx * diff;
      const float gr1 = kvy * diff;
      g0 = B1c * g0 + 0.1f * gr0;
      g1 = B1c * g1 + 0.1f * gr1;
      h0 = B2c * h0 + 0.001f * (gr0 * gr0);
      h1 = B2c * h1 + 0.001f * (gr1 * gr1);
      S0 -= lrb * g0 * __builtin_amdgcn_rcpf(h0 + 1.f);
      S1 -= lrb * g1 * __builtin_amdgcn_rcpf(h1 + 1.f);
      const float ro = reduce32(qvx * S0 + qvy * S1);
      if (kg == 0) op[(size_t)(t0 + s) * HK] = ro;  // lanes 0,32: one per col
      if (s + 1 < TC) { kqc = kqn; vbc = vbn; }
    }

    // write next tile into the other buffer; single barrier per tile
    if (more) {
      kq[d ^ 1][sr][sm * 2 + 0] = make_float4(nk.x, nk.y, nq.x, nq.y);
      kq[d ^ 1][sr][sm * 2 + 1] = make_float4(nk.z, nk.w, nq.z, nq.w);
      if (tid < 128) vb[d ^ 1][vr][v8] = make_float2(nv, nb);
    }
    __syncthreads();
  }
}

// ---------------------------------------------------------------------------
// RMSNorm over V=64 (in-place), * rms_w
// ---------------------------------------------------------------------------
__global__ __launch_bounds__(256) void rmsnorm_kernel(float* __restrict__ o,
                                                      const float* __restrict__ rmsw) {
  const int idx = blockIdx.x * 4 + (threadIdx.x >> 6);  // (b,t,h), 0..16383
  const int lane = threadIdx.x & 63;
  float* p = o + (size_t)idx * 64;
  float y = p[lane];
  float ss = y * y;
#pragma unroll
  for (int off = 32; off; off >>= 1) ss += __shfl_xor(ss, off, 64);
  y = y * rsqrtf(ss * (1.f / 64.f) + 1e-5f) * rmsw[lane];
  p[lane] = y;
}

// ---------------------------------------------------------------------------
extern "C" void kernel_launch(void* const* d_in, const int* in_sizes, int n_in,
                              void* d_out, int out_size, void* d_ws, size_t ws_size,
                              hipStream_t stream) {
  const float* x    = (const float*)d_in[0];
  const float* Wq   = (const float*)d_in[1];
  const float* Wk   = (const float*)d_in[2];
  const float* Wv   = (const float*)d_in[3];
  const float* Wb   = (const float*)d_in[4];
  const float* cwq  = (const float*)d_in[5];
  const float* cwk  = (const float*)d_in[6];
  const float* cwv  = (const float*)d_in[7];
  const float* rmsw = (const float*)d_in[8];
  const float* Wo   = (const float*)d_in[9];
  float* out = (float*)d_out;
  float* ws  = (float*)d_ws;

  const size_t SZ = (size_t)BT * HK;   // 1,048,576 floats
  float* qp   = ws;            // pre-conv q   (later reused as scan output)
  float* kp   = ws + 1 * SZ;
  float* vp   = ws + 2 * SZ;
  float* qc   = ws + 3 * SZ;
  float* kc   = ws + 4 * SZ;
  float* vc   = ws + 5 * SZ;
  float* beta = ws + 6 * SZ;   // 16384 floats
  float* on   = qp;            // scan output / rmsnorm in-place (qp dead then)

  // 1. projections q,k,v
  gemm3_kernel<<<dim3(BT / 64, HK / 64, 3), 256, 0, stream>>>(x, Wq, Wk, Wv, qp, kp, vp);
  // 2. beta
  beta_kernel<<<dim3(BT * Hh / 256), 256, 0, stream>>>(x, Wb, beta);
  // 3. conv + silu + l2norm
  conv_kernel<<<dim3(Bb * Tt * Hh / 4, 1, 3), 256, 0, stream>>>(
      qp, kp, vp, cwq, cwk, cwv, qc, kc, vc);
  // 4. sequential scan: 128 blocks x 4 waves; packed LDS operands
  scan_kernel<<<dim3(Bb * Hh * (Vv / 8)), 256, 0, stream>>>(
      qc, kc, vc, beta, on);
  // 5. RMSNorm (in-place)
  rmsnorm_kernel<<<dim3(Bb * Tt * Hh / 4), 256, 0, stream>>>(on, rmsw);
  // 6. output projection
  gemm1_kernel<<<dim3(BT / 64, HK / 64, 1), 256, 0, stream>>>(on, Wo, out);
}